// Round 5
// baseline (531.323 us; speedup 1.0000x reference)
//
#include <hip/hip_runtime.h>
#include <hip/hip_cooperative_groups.h>
#include <math.h>

namespace cg = cooperative_groups;

// ---------------------------------------------------------------------------
// DeepBilateralNetCurves (HDRNet) forward, f32.
// B=2, lowres 3x256x256, fullres 3x1024x1024, grid 12x8x16x16, 16-pt curve.
//
// Round 4: the 13-launch chain was dispatch-gap/latency bound (~100 us of the
// 167). Collapse everything into ONE cooperative kernel with 8 grid.sync()s;
// global & local paths run concurrently in shared phases. Fallback to the
// round-3 multi-kernel sequence if cooperative launch is rejected.
// ---------------------------------------------------------------------------

#define NBLK 256
#define NTHR 1024

struct HParams {
    const float *img_lo, *img_fr;
    const float *sw0, *sb0, *sw1, *sb1, *sw2, *sb2, *sw3, *sb3;
    const float *gw0, *gb0, *gw1, *gb1;
    const float *fw0, *fb0, *fw1, *fb1, *fw2, *fb2;
    const float *lw0, *lb0, *lw1;
    const float *pw, *pb;
    const float *ccm_w, *ccm_b, *shifts, *slopes, *proj_w, *proj_b;
    float *out;
    float *x0, *x1, *x2, *x3, *g0, *g1, *f0, *f1, *f2, *loc0, *loc1, *sco;
    int B;
};

// ---- device helpers (phase bodies) ----------------------------------------

__device__ __forceinline__ void conv3x3_chw_phase(
    const float* __restrict__ in, const float* __restrict__ wgt,
    const float* __restrict__ bias, float* __restrict__ out,
    int B, int Cin, int Hin, int Win, int Cout, int Hout, int Wout,
    int stride, int tid, int nth) {
    int total = B * Cout * Hout * Wout;
    for (int idx = tid; idx < total; idx += nth) {
        int wo = idx % Wout;
        int ho = (idx / Wout) % Hout;
        int co = (idx / (Wout * Hout)) % Cout;
        int b  = idx / (Wout * Hout * Cout);
        float acc = bias[co];
        int hb = ho * stride - 1, wb = wo * stride - 1;
        const float* wr = wgt + (size_t)co * Cin * 9;
        const float* ib = in + (size_t)b * Cin * Hin * Win;
        for (int ci = 0; ci < Cin; ++ci) {
            const float* ip = ib + (size_t)ci * Hin * Win;
            const float* wp = wr + ci * 9;
#pragma unroll
            for (int ky = 0; ky < 3; ++ky) {
                int hi = hb + ky;
                if (hi < 0 || hi >= Hin) continue;
#pragma unroll
                for (int kx = 0; kx < 3; ++kx) {
                    int wi = wb + kx;
                    if (wi < 0 || wi >= Win) continue;
                    acc += ip[hi * Win + wi] * wp[ky * 3 + kx];
                }
            }
        }
        out[idx] = fmaxf(acc, 0.0f);
    }
}

__device__ __forceinline__ void conv3x3_hwc_phase(
    const float* __restrict__ in, const float* __restrict__ wgt,
    const float* __restrict__ bias, float* __restrict__ out,
    int B, int Cin, int Hin, int Win, int Cout, int Hout, int Wout,
    int stride, int tid, int nth) {
    int total = B * Cout * Hout * Wout;
    for (int idx = tid; idx < total; idx += nth) {
        int co = idx % Cout;
        int wo = (idx / Cout) % Wout;
        int ho = (idx / (Cout * Wout)) % Hout;
        int b  = idx / (Cout * Wout * Hout);
        float acc = bias[co];
        int hb = ho * stride - 1, wb = wo * stride - 1;
        const float* wr = wgt + (size_t)co * Cin * 9;
        const float* ib = in + (size_t)b * Cin * Hin * Win;
        for (int ci = 0; ci < Cin; ++ci) {
            const float* ip = ib + (size_t)ci * Hin * Win;
            const float* wp = wr + ci * 9;
#pragma unroll
            for (int ky = 0; ky < 3; ++ky) {
                int hi = hb + ky;
                if (hi < 0 || hi >= Hin) continue;
#pragma unroll
                for (int kx = 0; kx < 3; ++kx) {
                    int wi = wb + kx;
                    if (wi < 0 || wi >= Win) continue;
                    acc += ip[hi * Win + wi] * wp[ky * 3 + kx];
                }
            }
        }
        out[idx] = fmaxf(acc, 0.0f);  // HWC flat index == idx
    }
}

// wave-per-output conv, HWC input, lane = ci. Cin=32 -> 2 co per wave.
__device__ __forceinline__ void conv_wave_phase(
    const float* __restrict__ in, const float* __restrict__ wgt,
    const float* __restrict__ bias, float* __restrict__ out,
    int B, int Cin, int Hin, int Win, int Cout, int Hout, int Wout,
    int stride, int relu, int out_chw, int wfirst, int wstride, int lane) {
    int copw = (Cin == 64) ? 1 : 2;
    int cow  = Cout / copw;
    int nw   = B * cow * Hout * Wout;
    int ci   = lane & (Cin - 1);
    for (int wid = wfirst; wid < nw; wid += wstride) {
        int cw = wid % cow;
        int wo = (wid / cow) % Wout;
        int ho = (wid / (cow * Wout)) % Hout;
        int b  = wid / (cow * Wout * Hout);
        int co = cw * copw + ((copw == 2) ? (lane >> 5) : 0);
        int hb = ho * stride - 1, wb = wo * stride - 1;
        const float* wp = wgt + ((size_t)co * Cin + ci) * 9;
        float acc = 0.0f;
#pragma unroll
        for (int ky = 0; ky < 3; ++ky) {
            int hi = hb + ky;
            if (hi < 0 || hi >= Hin) continue;
#pragma unroll
            for (int kx = 0; kx < 3; ++kx) {
                int wi = wb + kx;
                if (wi < 0 || wi >= Win) continue;
                acc += in[((size_t)(b * Hin + hi) * Win + wi) * Cin + ci] * wp[ky * 3 + kx];
            }
        }
        for (int m = 1; m < Cin; m <<= 1) acc += __shfl_xor(acc, m);
        if (ci == 0) {
            if (bias) acc += bias[co];
            if (relu) acc = fmaxf(acc, 0.0f);
            if (out_chw) out[((size_t)(b * Cout + co) * Hout + ho) * Wout + wo] = acc;
            else         out[((size_t)(b * Hout + ho) * Wout + wo) * Cout + co] = acc;
        }
    }
}

// ---- the single cooperative kernel ----------------------------------------

__global__ __launch_bounds__(NTHR, 4) void hdrnet_k(HParams p) {
    cg::grid_group grid = cg::this_grid();
    const int nth  = NBLK * NTHR;
    const int tid  = blockIdx.x * NTHR + threadIdx.x;
    const int lane = threadIdx.x & 63;
    const int gwv  = tid >> 6;
    const int nwv  = nth >> 6;
    const int B    = p.B;

    // P1: conv0 3->8, 256->128, CHW
    conv3x3_chw_phase(p.img_lo, p.sw0, p.sb0, p.x0, B, 3, 256, 256, 8, 128, 128, 2, tid, nth);
    grid.sync();
    // P2: conv1 8->16, 128->64, CHW
    conv3x3_chw_phase(p.x0, p.sw1, p.sb1, p.x1, B, 8, 128, 128, 16, 64, 64, 2, tid, nth);
    grid.sync();
    // P3: conv2 16->32, 64->32, CHW -> HWC
    conv3x3_hwc_phase(p.x1, p.sw2, p.sb2, p.x2, B, 16, 64, 64, 32, 32, 32, 2, tid, nth);
    grid.sync();
    // P4: conv3 32->64, 32->16 (wave, Cin=32), HWC
    conv_wave_phase(p.x2, p.sw3, p.sb3, p.x3, B, 32, 32, 32, 64, 16, 16, 2, 1, 0, gwv, nwv, lane);
    grid.sync();
    // P5: gconv0 (16->8) || lconv0 (16x16), both read x3
    if (gwv < 1024) conv_wave_phase(p.x3, p.gw0, p.gb0, p.g0,  B, 64, 16, 16, 64, 8, 8,  2, 1, 0, gwv, 1024, lane);
    else            conv_wave_phase(p.x3, p.lw0, p.lb0, p.loc0, B, 64, 16, 16, 64, 16, 16, 1, 1, 0, gwv - 1024, nwv - 1024, lane);
    grid.sync();
    // P6: gconv1 (8->4, CHW out for FC flatten) || lconv1
    if (gwv < 256)  conv_wave_phase(p.g0, p.gw1, p.gb1, p.g1,   B, 64, 8, 8,  64, 4, 4,  2, 1, 1, gwv, 256, lane);
    else            conv_wave_phase(p.loc0, p.lw1, nullptr, p.loc1, B, 64, 16, 16, 64, 16, 16, 1, 0, 0, gwv - 256, nwv - 256, lane);
    grid.sync();
    // P7: FC chain 1024->256->128->64 on blocks 0..B-1 (block-local syncs)
    if ((int)blockIdx.x < B) {
        int b  = blockIdx.x;
        int wl = threadIdx.x >> 6;
        const int nwl = NTHR >> 6;
        for (int o = wl; o < 256; o += nwl) {
            const float* ip = p.g1 + (size_t)b * 1024;
            const float* wp = p.fw0 + (size_t)o * 1024;
            float acc = 0.0f;
            for (int j = lane; j < 1024; j += 64) acc += ip[j] * wp[j];
            for (int m = 1; m < 64; m <<= 1) acc += __shfl_xor(acc, m);
            if (lane == 0) p.f0[b * 256 + o] = fmaxf(acc + p.fb0[o], 0.0f);
        }
        __syncthreads();
        for (int o = wl; o < 128; o += nwl) {
            const float* ip = p.f0 + (size_t)b * 256;
            const float* wp = p.fw1 + (size_t)o * 256;
            float acc = 0.0f;
            for (int j = lane; j < 256; j += 64) acc += ip[j] * wp[j];
            for (int m = 1; m < 64; m <<= 1) acc += __shfl_xor(acc, m);
            if (lane == 0) p.f1[b * 128 + o] = fmaxf(acc + p.fb1[o], 0.0f);
        }
        __syncthreads();
        for (int o = wl; o < 64; o += nwl) {
            const float* ip = p.f1 + (size_t)b * 128;
            const float* wp = p.fw2 + (size_t)o * 128;
            float acc = 0.0f;
            for (int j = lane; j < 128; j += 64) acc += ip[j] * wp[j];
            for (int m = 1; m < 64; m <<= 1) acc += __shfl_xor(acc, m);
            if (lane == 0) p.f2[b * 64 + o] = acc + p.fb2[o];
        }
    }
    grid.sync();
    // P8: fusion + 1x1 pred -> slicing layout sco[((b*16+y)*16+x)*96 + z*12+c]
    {
        int total = B * 256 * 96;
        for (int idx = tid; idx < total; idx += nth) {
            int c = idx % 96;
            int x = (idx / 96) & 15;
            int y = (idx / (96 * 16)) & 15;
            int b = idx / (96 * 256);
            float acc = p.pb[c];
            const float* wp = p.pw + (size_t)c * 64;
            const float* fb = p.f2 + (size_t)b * 64;
            const float* lb = p.loc1 + ((size_t)((b * 16 + y) * 16 + x)) * 64;
            for (int i = 0; i < 64; ++i) acc += wp[i] * fmaxf(fb[i] + lb[i], 0.0f);
            p.sco[idx] = acc;
        }
    }
    grid.sync();
    // P9: fullres guide + trilinear slice + affine apply
    {
        const int H = 1024, W = 1024;
        size_t plane = (size_t)H * W;
        int total = B * H * W;
        for (int idx = tid; idx < total; idx += nth) {
            int w = idx % W;
            int h = (idx / W) % H;
            int b = idx / (W * H);
            const float* ib = p.img_fr + (size_t)b * 3 * plane + (size_t)h * W + w;
            float r  = ib[0];
            float g  = ib[plane];
            float bl = ib[2 * plane];

            float gd = p.proj_b[0];
#pragma unroll
            for (int c = 0; c < 3; ++c) {
                float v = p.ccm_b[c] + p.ccm_w[c * 3 + 0] * r + p.ccm_w[c * 3 + 1] * g + p.ccm_w[c * 3 + 2] * bl;
                float acc = 0.0f;
#pragma unroll
                for (int q = 0; q < 16; ++q)
                    acc += p.slopes[c * 16 + q] * fmaxf(v - p.shifts[c * 16 + q], 0.0f);
                gd += p.proj_w[c] * acc;
            }
            gd = fminf(fmaxf(gd, 0.0f), 1.0f);

            float xs = ((float)w + 0.5f) * (16.0f / (float)W) - 0.5f;
            float ys = ((float)h + 0.5f) * (16.0f / (float)H) - 0.5f;
            float gz = gd * 8.0f - 0.5f;
            int fx = (int)floorf(xs);
            int fy = (int)floorf(ys);
            int fz = (int)floorf(gz);

            float coeff[12];
#pragma unroll
            for (int c = 0; c < 12; ++c) coeff[c] = 0.0f;

            const float* scob = p.sco + (size_t)b * 256 * 96;
#pragma unroll
            for (int dz = 0; dz < 2; ++dz) {
                int zi = min(max(fz + dz, 0), 7);
                float wz = fmaxf(1.0f - fabsf(gz - (float)(fz + dz)), 0.0f);
#pragma unroll
                for (int dy = 0; dy < 2; ++dy) {
                    int yi = min(max(fy + dy, 0), 15);
                    float wy = fmaxf(1.0f - fabsf(ys - (float)(fy + dy)), 0.0f);
#pragma unroll
                    for (int dx = 0; dx < 2; ++dx) {
                        int xi = min(max(fx + dx, 0), 15);
                        float wx = fmaxf(1.0f - fabsf(xs - (float)(fx + dx)), 0.0f);
                        float wt = wz * wy * wx;
                        const float4* gp = (const float4*)(scob + ((size_t)(yi * 16 + xi) * 96 + zi * 12));
                        float4 a0 = gp[0], a1 = gp[1], a2 = gp[2];
                        coeff[0]  += wt * a0.x; coeff[1]  += wt * a0.y; coeff[2]  += wt * a0.z; coeff[3]  += wt * a0.w;
                        coeff[4]  += wt * a1.x; coeff[5]  += wt * a1.y; coeff[6]  += wt * a1.z; coeff[7]  += wt * a1.w;
                        coeff[8]  += wt * a2.x; coeff[9]  += wt * a2.y; coeff[10] += wt * a2.z; coeff[11] += wt * a2.w;
                    }
                }
            }

            float* ob = p.out + (size_t)b * 3 * plane + (size_t)h * W + w;
#pragma unroll
            for (int o = 0; o < 3; ++o) {
                float v = coeff[o * 4 + 3] + coeff[o * 4 + 0] * r + coeff[o * 4 + 1] * g + coeff[o * 4 + 2] * bl;
                ob[o * plane] = fminf(fmaxf(v, 0.0f), 1.0f);
            }
        }
    }
}

// ---- fallback multi-kernel path (round-3, known-good) ---------------------

__global__ void fb_conv3x3_k(const float* __restrict__ in, const float* __restrict__ wgt,
                             const float* __restrict__ bias, float* __restrict__ out,
                             int B, int Cin, int Hin, int Win, int Cout, int Hout, int Wout,
                             int stride) {
    int total = B * Cout * Hout * Wout;
    int idx = blockIdx.x * blockDim.x + threadIdx.x;
    if (idx >= total) return;
    conv3x3_chw_phase(in, wgt, bias, out, B, Cin, Hin, Win, Cout, Hout, Wout, stride, idx, total + 1);
}

__global__ void fb_conv3x3_hwc_k(const float* __restrict__ in, const float* __restrict__ wgt,
                                 const float* __restrict__ bias, float* __restrict__ out,
                                 int B, int Cin, int Hin, int Win, int Cout, int Hout, int Wout,
                                 int stride) {
    int total = B * Cout * Hout * Wout;
    int idx = blockIdx.x * blockDim.x + threadIdx.x;
    if (idx >= total) return;
    conv3x3_hwc_phase(in, wgt, bias, out, B, Cin, Hin, Win, Cout, Hout, Wout, stride, idx, total + 1);
}

__global__ void fb_conv_wave_k(const float* __restrict__ in, const float* __restrict__ wgt,
                               const float* __restrict__ bias, float* __restrict__ out,
                               int B, int Cin, int Hin, int Win, int Cout, int Hout, int Wout,
                               int stride, int relu, int out_chw) {
    int tid  = blockIdx.x * blockDim.x + threadIdx.x;
    int wid  = tid >> 6;
    int lane = threadIdx.x & 63;
    int copw = (Cin == 64) ? 1 : 2;
    int nw   = B * (Cout / copw) * Hout * Wout;
    if (wid >= nw) return;
    conv_wave_phase(in, wgt, bias, out, B, Cin, Hin, Win, Cout, Hout, Wout,
                    stride, relu, out_chw, wid, nw + 1, lane);
}

__global__ void fb_fc_wave_k(const float* __restrict__ in, const float* __restrict__ wgt,
                             const float* __restrict__ bias, float* __restrict__ out,
                             int B, int IN, int OUT, int do_relu) {
    int tid  = blockIdx.x * blockDim.x + threadIdx.x;
    int wid  = tid >> 6;
    int lane = threadIdx.x & 63;
    if (wid >= B * OUT) return;
    int o = wid % OUT, b = wid / OUT;
    const float* ip = in + (size_t)b * IN;
    const float* wp = wgt + (size_t)o * IN;
    float acc = 0.0f;
    for (int j = lane; j < IN; j += 64) acc += ip[j] * wp[j];
    for (int m = 1; m < 64; m <<= 1) acc += __shfl_xor(acc, m);
    if (lane == 0) {
        acc += bias[o];
        if (do_relu) acc = fmaxf(acc, 0.0f);
        out[wid] = acc;
    }
}

__global__ void fb_pred_k(const float* __restrict__ loc1, const float* __restrict__ fc2,
                          const float* __restrict__ pw, const float* __restrict__ pb,
                          float* __restrict__ sco, int B) {
    int total = B * 16 * 16 * 96;
    int idx = blockIdx.x * blockDim.x + threadIdx.x;
    if (idx >= total) return;
    int c = idx % 96;
    int x = (idx / 96) & 15;
    int y = (idx / (96 * 16)) & 15;
    int b = idx / (96 * 256);
    float acc = pb[c];
    const float* wp = pw + (size_t)c * 64;
    const float* fb = fc2 + (size_t)b * 64;
    const float* lb = loc1 + ((size_t)((b * 16 + y) * 16 + x)) * 64;
    for (int i = 0; i < 64; ++i) acc += wp[i] * fmaxf(fb[i] + lb[i], 0.0f);
    sco[idx] = acc;
}

__global__ void fb_apply_k(const float* __restrict__ img, const float* __restrict__ sco,
                           const float* __restrict__ ccm_w, const float* __restrict__ ccm_b,
                           const float* __restrict__ shifts, const float* __restrict__ slopes,
                           const float* __restrict__ proj_w, const float* __restrict__ proj_b,
                           float* __restrict__ out, int B, int H, int W) {
    int total = B * H * W;
    int idx = blockIdx.x * blockDim.x + threadIdx.x;
    if (idx >= total) return;
    int w = idx % W;
    int h = (idx / W) % H;
    int b = idx / (W * H);
    size_t plane = (size_t)H * W;
    const float* ib = img + (size_t)b * 3 * plane + (size_t)h * W + w;
    float r  = ib[0];
    float g  = ib[plane];
    float bl = ib[2 * plane];
    float gd = proj_b[0];
#pragma unroll
    for (int c = 0; c < 3; ++c) {
        float v = ccm_b[c] + ccm_w[c * 3 + 0] * r + ccm_w[c * 3 + 1] * g + ccm_w[c * 3 + 2] * bl;
        float acc = 0.0f;
#pragma unroll
        for (int q = 0; q < 16; ++q)
            acc += slopes[c * 16 + q] * fmaxf(v - shifts[c * 16 + q], 0.0f);
        gd += proj_w[c] * acc;
    }
    gd = fminf(fmaxf(gd, 0.0f), 1.0f);
    float xs = ((float)w + 0.5f) * (16.0f / (float)W) - 0.5f;
    float ys = ((float)h + 0.5f) * (16.0f / (float)H) - 0.5f;
    float gz = gd * 8.0f - 0.5f;
    int fx = (int)floorf(xs);
    int fy = (int)floorf(ys);
    int fz = (int)floorf(gz);
    float coeff[12];
#pragma unroll
    for (int c = 0; c < 12; ++c) coeff[c] = 0.0f;
    const float* scob = sco + (size_t)b * 256 * 96;
#pragma unroll
    for (int dz = 0; dz < 2; ++dz) {
        int zi = min(max(fz + dz, 0), 7);
        float wz = fmaxf(1.0f - fabsf(gz - (float)(fz + dz)), 0.0f);
#pragma unroll
        for (int dy = 0; dy < 2; ++dy) {
            int yi = min(max(fy + dy, 0), 15);
            float wy = fmaxf(1.0f - fabsf(ys - (float)(fy + dy)), 0.0f);
#pragma unroll
            for (int dx = 0; dx < 2; ++dx) {
                int xi = min(max(fx + dx, 0), 15);
                float wx = fmaxf(1.0f - fabsf(xs - (float)(fx + dx)), 0.0f);
                float wt = wz * wy * wx;
                const float4* gp = (const float4*)(scob + ((size_t)(yi * 16 + xi) * 96 + zi * 12));
                float4 a0 = gp[0], a1 = gp[1], a2 = gp[2];
                coeff[0]  += wt * a0.x; coeff[1]  += wt * a0.y; coeff[2]  += wt * a0.z; coeff[3]  += wt * a0.w;
                coeff[4]  += wt * a1.x; coeff[5]  += wt * a1.y; coeff[6]  += wt * a1.z; coeff[7]  += wt * a1.w;
                coeff[8]  += wt * a2.x; coeff[9]  += wt * a2.y; coeff[10] += wt * a2.z; coeff[11] += wt * a2.w;
            }
        }
    }
    float* ob = out + (size_t)b * 3 * plane + (size_t)h * W + w;
#pragma unroll
    for (int o = 0; o < 3; ++o) {
        float v = coeff[o * 4 + 3] + coeff[o * 4 + 0] * r + coeff[o * 4 + 1] * g + coeff[o * 4 + 2] * bl;
        ob[o * plane] = fminf(fmaxf(v, 0.0f), 1.0f);
    }
}

static inline int cdiv(int a, int b) { return (a + b - 1) / b; }

extern "C" void kernel_launch(void* const* d_in, const int* in_sizes, int n_in,
                              void* d_out, int out_size, void* d_ws, size_t ws_size,
                              hipStream_t stream) {
    const float* img_lo = (const float*)d_in[0];
    const float* img_fr = (const float*)d_in[1];
    const float* sw0 = (const float*)d_in[2];  const float* sb0 = (const float*)d_in[3];
    const float* sw1 = (const float*)d_in[4];  const float* sb1 = (const float*)d_in[5];
    const float* sw2 = (const float*)d_in[6];  const float* sb2 = (const float*)d_in[7];
    const float* sw3 = (const float*)d_in[8];  const float* sb3 = (const float*)d_in[9];
    const float* gw0 = (const float*)d_in[10]; const float* gb0 = (const float*)d_in[11];
    const float* gw1 = (const float*)d_in[12]; const float* gb1 = (const float*)d_in[13];
    const float* fw0 = (const float*)d_in[14]; const float* fb0 = (const float*)d_in[15];
    const float* fw1 = (const float*)d_in[16]; const float* fb1 = (const float*)d_in[17];
    const float* fw2 = (const float*)d_in[18]; const float* fb2 = (const float*)d_in[19];
    const float* lw0 = (const float*)d_in[20]; const float* lb0 = (const float*)d_in[21];
    const float* lw1 = (const float*)d_in[22];
    const float* pw  = (const float*)d_in[23]; const float* pb  = (const float*)d_in[24];
    const float* ccm_w  = (const float*)d_in[25]; const float* ccm_b = (const float*)d_in[26];
    const float* shifts = (const float*)d_in[27];
    const float* slopes = (const float*)d_in[28];
    const float* proj_w = (const float*)d_in[29];
    const float* proj_b = (const float*)d_in[30];
    float* out = (float*)d_out;

    const int B = in_sizes[0] / (3 * 256 * 256);   // = 2
    const int H = 1024, W = 1024;

    float* ws = (float*)d_ws;
    float* x0   = ws;
    float* x1   = x0 + (size_t)B * 8  * 128 * 128;
    float* x2   = x1 + (size_t)B * 16 * 64 * 64;
    float* x3   = x2 + (size_t)B * 32 * 32 * 32;
    float* g0   = x3 + (size_t)B * 64 * 16 * 16;
    float* g1   = g0 + (size_t)B * 64 * 8 * 8;
    float* f0   = g1 + (size_t)B * 64 * 4 * 4;
    float* f1   = f0 + (size_t)B * 256;
    float* f2   = f1 + (size_t)B * 128;
    float* loc0 = f2 + (size_t)B * 64;
    float* loc1 = loc0 + (size_t)B * 64 * 16 * 16;
    float* sco  = loc1 + (size_t)B * 64 * 16 * 16;

    HParams p;
    p.img_lo = img_lo; p.img_fr = img_fr;
    p.sw0 = sw0; p.sb0 = sb0; p.sw1 = sw1; p.sb1 = sb1;
    p.sw2 = sw2; p.sb2 = sb2; p.sw3 = sw3; p.sb3 = sb3;
    p.gw0 = gw0; p.gb0 = gb0; p.gw1 = gw1; p.gb1 = gb1;
    p.fw0 = fw0; p.fb0 = fb0; p.fw1 = fw1; p.fb1 = fb1; p.fw2 = fw2; p.fb2 = fb2;
    p.lw0 = lw0; p.lb0 = lb0; p.lw1 = lw1;
    p.pw = pw; p.pb = pb;
    p.ccm_w = ccm_w; p.ccm_b = ccm_b; p.shifts = shifts; p.slopes = slopes;
    p.proj_w = proj_w; p.proj_b = proj_b;
    p.out = out;
    p.x0 = x0; p.x1 = x1; p.x2 = x2; p.x3 = x3;
    p.g0 = g0; p.g1 = g1; p.f0 = f0; p.f1 = f1; p.f2 = f2;
    p.loc0 = loc0; p.loc1 = loc1; p.sco = sco;
    p.B = B;

    void* kargs[] = { (void*)&p };
    hipError_t ce = hipLaunchCooperativeKernel((const void*)hdrnet_k,
                                               dim3(NBLK), dim3(NTHR), kargs, 0, stream);
    if (ce == hipSuccess) return;

    // ---- fallback: round-3 multi-kernel sequence ----
    const int T = 256;
    fb_conv3x3_k<<<cdiv(B * 8 * 128 * 128, T), T, 0, stream>>>(img_lo, sw0, sb0, x0, B, 3, 256, 256, 8, 128, 128, 2);
    fb_conv3x3_k<<<cdiv(B * 16 * 64 * 64, T), T, 0, stream>>>(x0, sw1, sb1, x1, B, 8, 128, 128, 16, 64, 64, 2);
    fb_conv3x3_hwc_k<<<cdiv(B * 32 * 32 * 32, T), T, 0, stream>>>(x1, sw2, sb2, x2, B, 16, 64, 64, 32, 32, 32, 2);
    fb_conv_wave_k<<<cdiv(B * 32 * 16 * 16 * 64, T), T, 0, stream>>>(x2, sw3, sb3, x3, B, 32, 32, 32, 64, 16, 16, 2, 1, 0);
    fb_conv_wave_k<<<cdiv(B * 64 * 8 * 8 * 64, T), T, 0, stream>>>(x3, gw0, gb0, g0, B, 64, 16, 16, 64, 8, 8, 2, 1, 0);
    fb_conv_wave_k<<<cdiv(B * 64 * 4 * 4 * 64, T), T, 0, stream>>>(g0, gw1, gb1, g1, B, 64, 8, 8, 64, 4, 4, 2, 1, 1);
    fb_fc_wave_k<<<cdiv(B * 256 * 64, T), T, 0, stream>>>(g1, fw0, fb0, f0, B, 1024, 256, 1);
    fb_fc_wave_k<<<cdiv(B * 128 * 64, T), T, 0, stream>>>(f0, fw1, fb1, f1, B, 256, 128, 1);
    fb_fc_wave_k<<<cdiv(B * 64 * 64, T), T, 0, stream>>>(f1, fw2, fb2, f2, B, 128, 64, 0);
    fb_conv_wave_k<<<cdiv(B * 64 * 16 * 16 * 64, T), T, 0, stream>>>(x3, lw0, lb0, loc0, B, 64, 16, 16, 64, 16, 16, 1, 1, 0);
    fb_conv_wave_k<<<cdiv(B * 64 * 16 * 16 * 64, T), T, 0, stream>>>(loc0, lw1, nullptr, loc1, B, 64, 16, 16, 64, 16, 16, 1, 0, 0);
    fb_pred_k<<<cdiv(B * 256 * 96, T), T, 0, stream>>>(loc1, f2, pw, pb, sco, B);
    fb_apply_k<<<cdiv(B * H * W, T), T, 0, stream>>>(img_fr, sco, ccm_w, ccm_b, shifts, slopes,
                                                     proj_w, proj_b, out, B, H, W);
}

// Round 6
// 253.924 us; speedup vs baseline: 2.0924x; 2.0924x over previous
//
#include <hip/hip_runtime.h>
#include <math.h>

// ---------------------------------------------------------------------------
// DeepBilateralNetCurves (HDRNet) forward, f32.
// B=2, lowres 3x256x256, fullres 3x1024x1024, grid 12x8x16x16, 16-pt curve.
//
// Round 5: cooperative grid.sync measured ~55us/sync on gfx950 -> abandoned.
// Back to multi-kernel, launches cut 13 -> 8:
//   conv0, conv1, conv2, conv3, {gconv0||lconv0}, {gconv1||lconv1},
//   {fc0+fc1+fc2}, {pred+guide+slice+apply (tiled, LDS-staged)}.
// ---------------------------------------------------------------------------

static inline int cdiv(int a, int b) { return (a + b - 1) / b; }

// ---- wide naive 3x3 convs (small Cin) --------------------------------------

__global__ void conv3x3_chw_k(const float* __restrict__ in, const float* __restrict__ wgt,
                              const float* __restrict__ bias, float* __restrict__ out,
                              int B, int Cin, int Hin, int Win,
                              int Cout, int Hout, int Wout, int stride) {
    int total = B * Cout * Hout * Wout;
    int idx = blockIdx.x * blockDim.x + threadIdx.x;
    if (idx >= total) return;
    int wo = idx % Wout;
    int ho = (idx / Wout) % Hout;
    int co = (idx / (Wout * Hout)) % Cout;
    int b  = idx / (Wout * Hout * Cout);
    float acc = bias[co];
    int hb = ho * stride - 1, wb = wo * stride - 1;
    const float* wr = wgt + (size_t)co * Cin * 9;
    const float* ib = in + (size_t)b * Cin * Hin * Win;
    for (int ci = 0; ci < Cin; ++ci) {
        const float* ip = ib + (size_t)ci * Hin * Win;
        const float* wp = wr + ci * 9;
#pragma unroll
        for (int ky = 0; ky < 3; ++ky) {
            int hi = hb + ky;
            if (hi < 0 || hi >= Hin) continue;
#pragma unroll
            for (int kx = 0; kx < 3; ++kx) {
                int wi = wb + kx;
                if (wi < 0 || wi >= Win) continue;
                acc += ip[hi * Win + wi] * wp[ky * 3 + kx];
            }
        }
    }
    out[idx] = fmaxf(acc, 0.0f);
}

__global__ void conv3x3_hwc_k(const float* __restrict__ in, const float* __restrict__ wgt,
                              const float* __restrict__ bias, float* __restrict__ out,
                              int B, int Cin, int Hin, int Win,
                              int Cout, int Hout, int Wout, int stride) {
    int total = B * Cout * Hout * Wout;
    int idx = blockIdx.x * blockDim.x + threadIdx.x;
    if (idx >= total) return;
    int co = idx % Cout;
    int wo = (idx / Cout) % Wout;
    int ho = (idx / (Cout * Wout)) % Hout;
    int b  = idx / (Cout * Wout * Hout);
    float acc = bias[co];
    int hb = ho * stride - 1, wb = wo * stride - 1;
    const float* wr = wgt + (size_t)co * Cin * 9;
    const float* ib = in + (size_t)b * Cin * Hin * Win;
    for (int ci = 0; ci < Cin; ++ci) {
        const float* ip = ib + (size_t)ci * Hin * Win;
        const float* wp = wr + ci * 9;
#pragma unroll
        for (int ky = 0; ky < 3; ++ky) {
            int hi = hb + ky;
            if (hi < 0 || hi >= Hin) continue;
#pragma unroll
            for (int kx = 0; kx < 3; ++kx) {
                int wi = wb + kx;
                if (wi < 0 || wi >= Win) continue;
                acc += ip[hi * Win + wi] * wp[ky * 3 + kx];
            }
        }
    }
    out[idx] = fmaxf(acc, 0.0f);  // idx == HWC flat index
}

// ---- wave-per-output conv (HWC input, lane = ci) ---------------------------

__device__ __forceinline__ void wave_conv_one(
    const float* __restrict__ in, const float* __restrict__ wgt,
    const float* __restrict__ bias, float* __restrict__ out,
    int B, int Cin, int Hin, int Win, int Cout, int Hout, int Wout,
    int stride, int relu, int out_chw, int wid, int lane) {
    int copw = (Cin == 64) ? 1 : 2;
    int cow  = Cout / copw;
    int ci   = lane & (Cin - 1);
    int cw = wid % cow;
    int wo = (wid / cow) % Wout;
    int ho = (wid / (cow * Wout)) % Hout;
    int b  = wid / (cow * Wout * Hout);
    int co = cw * copw + ((copw == 2) ? (lane >> 5) : 0);
    int hb = ho * stride - 1, wb = wo * stride - 1;
    const float* wp = wgt + ((size_t)co * Cin + ci) * 9;
    float acc = 0.0f;
#pragma unroll
    for (int ky = 0; ky < 3; ++ky) {
        int hi = hb + ky;
        if (hi < 0 || hi >= Hin) continue;
#pragma unroll
        for (int kx = 0; kx < 3; ++kx) {
            int wi = wb + kx;
            if (wi < 0 || wi >= Win) continue;
            acc += in[((size_t)(b * Hin + hi) * Win + wi) * Cin + ci] * wp[ky * 3 + kx];
        }
    }
    for (int m = 1; m < Cin; m <<= 1) acc += __shfl_xor(acc, m);
    if (ci == 0) {
        if (bias) acc += bias[co];
        if (relu) acc = fmaxf(acc, 0.0f);
        if (out_chw) out[((size_t)(b * Cout + co) * Hout + ho) * Wout + wo] = acc;
        else         out[((size_t)(b * Hout + ho) * Wout + wo) * Cout + co] = acc;
    }
}

// conv3: 32->64, 32x32 -> 16x16, stride 2, HWC->HWC
__global__ void conv3_k(const float* __restrict__ x2, const float* __restrict__ w,
                        const float* __restrict__ bias, float* __restrict__ x3, int B) {
    int tid = blockIdx.x * blockDim.x + threadIdx.x;
    int wid = tid >> 6, lane = threadIdx.x & 63;
    int nw = B * 32 * 16 * 16;  // copw=2 -> 32 co-groups
    if (wid >= nw) return;
    wave_conv_one(x2, w, bias, x3, B, 32, 32, 32, 64, 16, 16, 2, 1, 0, wid, lane);
}

// gconv0 (64ch 16->8, s2) || lconv0 (64ch 16x16, s1, relu)
__global__ void gl0_k(const float* __restrict__ x3,
                      const float* __restrict__ gw, const float* __restrict__ gb, float* __restrict__ g0,
                      const float* __restrict__ lw, const float* __restrict__ lb, float* __restrict__ loc0,
                      int B) {
    int tid = blockIdx.x * blockDim.x + threadIdx.x;
    int wid = tid >> 6, lane = threadIdx.x & 63;
    int ng = B * 64 * 8 * 8;
    int nl = B * 64 * 16 * 16;
    if (wid < ng)            wave_conv_one(x3, gw, gb, g0,  B, 64, 16, 16, 64, 8, 8,  2, 1, 0, wid, lane);
    else if (wid < ng + nl)  wave_conv_one(x3, lw, lb, loc0, B, 64, 16, 16, 64, 16, 16, 1, 1, 0, wid - ng, lane);
}

// gconv1 (64ch 8->4, s2, CHW out for FC flatten) || lconv1 (no relu)
__global__ void gl1_k(const float* __restrict__ g0, const float* __restrict__ loc0,
                      const float* __restrict__ gw, const float* __restrict__ gb, float* __restrict__ g1,
                      const float* __restrict__ lw, float* __restrict__ loc1, int B) {
    int tid = blockIdx.x * blockDim.x + threadIdx.x;
    int wid = tid >> 6, lane = threadIdx.x & 63;
    int ng = B * 64 * 4 * 4;
    int nl = B * 64 * 16 * 16;
    if (wid < ng)            wave_conv_one(g0, gw, gb, g1,   B, 64, 8, 8,  64, 4, 4,  2, 1, 1, wid, lane);
    else if (wid < ng + nl)  wave_conv_one(loc0, lw, nullptr, loc1, B, 64, 16, 16, 64, 16, 16, 1, 0, 0, wid - ng, lane);
}

// ---- FC chain: 1024 -> 256 -> 128 -> 64, one block per batch ---------------

__global__ __launch_bounds__(1024) void fc_chain_k(
    const float* __restrict__ g1,
    const float* __restrict__ fw0, const float* __restrict__ fb0,
    const float* __restrict__ fw1, const float* __restrict__ fb1,
    const float* __restrict__ fw2, const float* __restrict__ fb2,
    float* __restrict__ f2out) {
    __shared__ float s0[256];
    __shared__ float s1[128];
    int b = blockIdx.x;
    int wl = threadIdx.x >> 6, lane = threadIdx.x & 63;
    const int nwl = 16;
    const float* ip = g1 + (size_t)b * 1024;
    for (int o = wl; o < 256; o += nwl) {
        const float* wp = fw0 + (size_t)o * 1024;
        float acc = 0.0f;
        for (int j = lane; j < 1024; j += 64) acc += ip[j] * wp[j];
        for (int m = 1; m < 64; m <<= 1) acc += __shfl_xor(acc, m);
        if (lane == 0) s0[o] = fmaxf(acc + fb0[o], 0.0f);
    }
    __syncthreads();
    for (int o = wl; o < 128; o += nwl) {
        const float* wp = fw1 + (size_t)o * 256;
        float acc = 0.0f;
        for (int j = lane; j < 256; j += 64) acc += s0[j] * wp[j];
        for (int m = 1; m < 64; m <<= 1) acc += __shfl_xor(acc, m);
        if (lane == 0) s1[o] = fmaxf(acc + fb1[o], 0.0f);
    }
    __syncthreads();
    for (int o = wl; o < 64; o += nwl) {
        const float* wp = fw2 + (size_t)o * 128;
        float acc = 0.0f;
        for (int j = lane; j < 128; j += 64) acc += s1[j] * wp[j];
        for (int m = 1; m < 64; m <<= 1) acc += __shfl_xor(acc, m);
        if (lane == 0) f2out[b * 64 + o] = acc + fb2[o];
    }
}

// ---- fused pred + guide + trilinear slice + affine apply --------------------
// One block per 64x64 pixel tile. The tile's slice footprint is exactly the
// 3x3 grid-cell neighborhood (cells are 64x64 px). Stage pw/pb/loc1/f2/curve
// params in LDS, compute the footprint's 864 grid coeffs (pred) in LDS, then
// per-pixel guide+slice+apply with all coeff reads from LDS.

__global__ __launch_bounds__(256) void apply_k(
    const float* __restrict__ img, const float* __restrict__ loc1,
    const float* __restrict__ f2g,
    const float* __restrict__ pw, const float* __restrict__ pb,
    const float* __restrict__ ccm_w, const float* __restrict__ ccm_b,
    const float* __restrict__ shifts, const float* __restrict__ slopes,
    const float* __restrict__ proj_w, const float* __restrict__ proj_b,
    float* __restrict__ out) {
    __shared__ float s_pw[96 * 65];                 // padded: bank-safe per-lane c
    __shared__ float s_pb[96];
    __shared__ __align__(16) float s_sco[9 * 96];   // 3x3 cells x (z*12+c)
    __shared__ __align__(16) float s_loc[9 * 64];
    __shared__ float s_f2[64];
    __shared__ float s_shift[48], s_slope[48], s_ccmw[9], s_ccmb[3], s_projw[3], s_projb[1];

    const int t   = threadIdx.x;
    const int b   = blockIdx.x >> 8;
    const int rem = blockIdx.x & 255;
    const int ty  = rem >> 4;
    const int tx  = rem & 15;

    // ---- stage params ----
    {
        const float4* pw4 = (const float4*)pw;      // [96][64] -> 1536 float4
        for (int j = t; j < 1536; j += 256) {
            float4 v = pw4[j];
            int base = j * 4;
            int c = base >> 6, i = base & 63;
            float* dst = &s_pw[c * 65 + i];
            dst[0] = v.x; dst[1] = v.y; dst[2] = v.z; dst[3] = v.w;
        }
        if (t < 96) s_pb[t] = pb[t];
        if (t < 64) s_f2[t] = f2g[b * 64 + t];
        if (t < 48) { s_shift[t] = shifts[t]; s_slope[t] = slopes[t]; }
        if (t < 9)  s_ccmw[t] = ccm_w[t];
        if (t < 3)  { s_ccmb[t] = ccm_b[t]; s_projw[t] = proj_w[t]; }
        if (t == 0) s_projb[0] = proj_b[0];
        for (int j = t; j < 9 * 16; j += 256) {     // loc1: 9 cells x 64 ch as float4
            int cell = j >> 4, i4 = j & 15;
            int ly = cell / 3, lx = cell % 3;
            int gy = min(max(ty - 1 + ly, 0), 15);
            int gx = min(max(tx - 1 + lx, 0), 15);
            float4 v = ((const float4*)(loc1 + ((size_t)((b * 16 + gy) * 16 + gx)) * 64))[i4];
            ((float4*)(s_loc + cell * 64))[i4] = v;
        }
    }
    __syncthreads();

    // ---- pred: sco[cell][z*12+c] = pb + pw . relu(f2 + loc1[cell]) ----
    for (int o = t; o < 9 * 96; o += 256) {
        int cell = o / 96, c = o % 96;
        float acc = s_pb[c];
        const float* wp = &s_pw[c * 65];
        const float* lp = &s_loc[cell * 64];
        for (int i = 0; i < 64; ++i)
            acc += wp[i] * fmaxf(s_f2[i] + lp[i], 0.0f);
        s_sco[cell * 96 + c] = acc;
    }
    __syncthreads();

    // ---- per-pixel: guide -> slice (from LDS) -> affine apply ----
    const size_t plane = 1024 * 1024;
    const float* ibase = img + (size_t)b * 3 * plane;
    float* obase = out + (size_t)b * 3 * plane;
    for (int it = 0; it < 16; ++it) {
        int pxi = it * 256 + t;
        int row = pxi >> 6, col = pxi & 63;
        int y = ty * 64 + row, x = tx * 64 + col;
        size_t off = (size_t)y * 1024 + x;
        float r  = ibase[off];
        float g  = ibase[plane + off];
        float bl = ibase[2 * plane + off];

        float gd = s_projb[0];
#pragma unroll
        for (int c = 0; c < 3; ++c) {
            float v = s_ccmb[c] + s_ccmw[c * 3 + 0] * r + s_ccmw[c * 3 + 1] * g + s_ccmw[c * 3 + 2] * bl;
            float acc = 0.0f;
#pragma unroll
            for (int p = 0; p < 16; ++p)
                acc += s_slope[c * 16 + p] * fmaxf(v - s_shift[c * 16 + p], 0.0f);
            gd += s_projw[c] * acc;
        }
        gd = fminf(fmaxf(gd, 0.0f), 1.0f);

        float xs = ((float)x + 0.5f) * 0.015625f - 0.5f;   // *16/1024
        float ys = ((float)y + 0.5f) * 0.015625f - 0.5f;
        float gz = gd * 8.0f - 0.5f;
        int fx = (int)floorf(xs);
        int fy = (int)floorf(ys);
        int fz = (int)floorf(gz);

        float coeff[12];
#pragma unroll
        for (int c = 0; c < 12; ++c) coeff[c] = 0.0f;

#pragma unroll
        for (int dz = 0; dz < 2; ++dz) {
            int zi = min(max(fz + dz, 0), 7);
            float wz = fmaxf(1.0f - fabsf(gz - (float)(fz + dz)), 0.0f);
#pragma unroll
            for (int dy = 0; dy < 2; ++dy) {
                int ly = (fy + dy) - (ty - 1);             // in {0,1,2}; staging clamped
                float wy = fmaxf(1.0f - fabsf(ys - (float)(fy + dy)), 0.0f);
#pragma unroll
                for (int dx = 0; dx < 2; ++dx) {
                    int lx = (fx + dx) - (tx - 1);         // in {0,1,2}
                    float wx = fmaxf(1.0f - fabsf(xs - (float)(fx + dx)), 0.0f);
                    float wt = wz * wy * wx;
                    const float4* gp = (const float4*)(s_sco + ((ly * 3 + lx) * 96 + zi * 12));
                    float4 a0 = gp[0], a1 = gp[1], a2 = gp[2];
                    coeff[0]  += wt * a0.x; coeff[1]  += wt * a0.y; coeff[2]  += wt * a0.z; coeff[3]  += wt * a0.w;
                    coeff[4]  += wt * a1.x; coeff[5]  += wt * a1.y; coeff[6]  += wt * a1.z; coeff[7]  += wt * a1.w;
                    coeff[8]  += wt * a2.x; coeff[9]  += wt * a2.y; coeff[10] += wt * a2.z; coeff[11] += wt * a2.w;
                }
            }
        }

#pragma unroll
        for (int o = 0; o < 3; ++o) {
            float v = coeff[o * 4 + 3] + coeff[o * 4 + 0] * r + coeff[o * 4 + 1] * g + coeff[o * 4 + 2] * bl;
            obase[o * plane + off] = fminf(fmaxf(v, 0.0f), 1.0f);
        }
    }
}

// ---------------------------------------------------------------------------

extern "C" void kernel_launch(void* const* d_in, const int* in_sizes, int n_in,
                              void* d_out, int out_size, void* d_ws, size_t ws_size,
                              hipStream_t stream) {
    const float* img_lo = (const float*)d_in[0];
    const float* img_fr = (const float*)d_in[1];
    const float* sw0 = (const float*)d_in[2];  const float* sb0 = (const float*)d_in[3];
    const float* sw1 = (const float*)d_in[4];  const float* sb1 = (const float*)d_in[5];
    const float* sw2 = (const float*)d_in[6];  const float* sb2 = (const float*)d_in[7];
    const float* sw3 = (const float*)d_in[8];  const float* sb3 = (const float*)d_in[9];
    const float* gw0 = (const float*)d_in[10]; const float* gb0 = (const float*)d_in[11];
    const float* gw1 = (const float*)d_in[12]; const float* gb1 = (const float*)d_in[13];
    const float* fw0 = (const float*)d_in[14]; const float* fb0 = (const float*)d_in[15];
    const float* fw1 = (const float*)d_in[16]; const float* fb1 = (const float*)d_in[17];
    const float* fw2 = (const float*)d_in[18]; const float* fb2 = (const float*)d_in[19];
    const float* lw0 = (const float*)d_in[20]; const float* lb0 = (const float*)d_in[21];
    const float* lw1 = (const float*)d_in[22];
    const float* pw  = (const float*)d_in[23]; const float* pb  = (const float*)d_in[24];
    const float* ccm_w  = (const float*)d_in[25]; const float* ccm_b = (const float*)d_in[26];
    const float* shifts = (const float*)d_in[27];
    const float* slopes = (const float*)d_in[28];
    const float* proj_w = (const float*)d_in[29];
    const float* proj_b = (const float*)d_in[30];
    float* out = (float*)d_out;

    const int B = in_sizes[0] / (3 * 256 * 256);   // = 2

    // workspace carve (floats)
    float* ws = (float*)d_ws;
    float* x0   = ws;                                // B*8*128*128   CHW
    float* x1   = x0 + (size_t)B * 8  * 128 * 128;   // B*16*64*64    CHW
    float* x2   = x1 + (size_t)B * 16 * 64 * 64;     // B*32*32*32    HWC
    float* x3   = x2 + (size_t)B * 32 * 32 * 32;     // B*16*16*64    HWC
    float* g0   = x3 + (size_t)B * 64 * 16 * 16;     // B*8*8*64      HWC
    float* g1   = g0 + (size_t)B * 64 * 8 * 8;       // B*64*4*4      CHW
    float* f2   = g1 + (size_t)B * 64 * 4 * 4;       // B*64
    float* loc0 = f2 + (size_t)B * 64;               // B*16*16*64    HWC
    float* loc1 = loc0 + (size_t)B * 64 * 16 * 16;   // B*16*16*64    HWC

    const int T = 256;

    // 1-3: splat chain (wide)
    conv3x3_chw_k<<<cdiv(B * 8 * 128 * 128, T), T, 0, stream>>>(img_lo, sw0, sb0, x0, B, 3, 256, 256, 8, 128, 128, 2);
    conv3x3_chw_k<<<cdiv(B * 16 * 64 * 64, T), T, 0, stream>>>(x0, sw1, sb1, x1, B, 8, 128, 128, 16, 64, 64, 2);
    conv3x3_hwc_k<<<cdiv(B * 32 * 32 * 32, T), T, 0, stream>>>(x1, sw2, sb2, x2, B, 16, 64, 64, 32, 32, 32, 2);
    // 4: conv3 (wave)
    conv3_k<<<cdiv(B * 32 * 16 * 16 * 64, T), T, 0, stream>>>(x2, sw3, sb3, x3, B);
    // 5: gconv0 || lconv0
    {
        int nwaves = B * 64 * 8 * 8 + B * 64 * 16 * 16;
        gl0_k<<<cdiv(nwaves * 64, T), T, 0, stream>>>(x3, gw0, gb0, g0, lw0, lb0, loc0, B);
    }
    // 6: gconv1 || lconv1
    {
        int nwaves = B * 64 * 4 * 4 + B * 64 * 16 * 16;
        gl1_k<<<cdiv(nwaves * 64, T), T, 0, stream>>>(g0, loc0, gw1, gb1, g1, lw1, loc1, B);
    }
    // 7: FC chain (one block per batch)
    fc_chain_k<<<B, 1024, 0, stream>>>(g1, fw0, fb0, fw1, fb1, fw2, fb2, f2);
    // 8: fused pred + guide + slice + apply (64x64-px tiles)
    apply_k<<<B * 256, 256, 0, stream>>>(img_fr, loc1, f2, pw, pb, ccm_w, ccm_b,
                                         shifts, slopes, proj_w, proj_b, out);
}

// Round 7
// 192.248 us; speedup vs baseline: 2.7637x; 1.3208x over previous
//
#include <hip/hip_runtime.h>
#include <math.h>

// ---------------------------------------------------------------------------
// DeepBilateralNetCurves (HDRNet) forward, f32.
// B=2, lowres 3x256x256, fullres 3x1024x1024, grid 12x8x16x16, 16-pt curve.
//
// Round 6 post-mortem: fc_chain_k at grid=2 blocks was latency-bound (145us,
// 0.36% occupancy). Round 7: fc0 goes back to a wide wave-per-output kernel;
// fc1+fc2 are folded into apply_k's preamble (redundant per block, L2-hot
// weights). 8 launches total:
//   conv0, conv1, conv2, conv3, {gconv0||lconv0}, {gconv1||lconv1}, fc0,
//   {fc1+fc2+pred+guide+slice+apply}.
// ---------------------------------------------------------------------------

static inline int cdiv(int a, int b) { return (a + b - 1) / b; }

// ---- wide naive 3x3 convs (small Cin) --------------------------------------

__global__ void conv3x3_chw_k(const float* __restrict__ in, const float* __restrict__ wgt,
                              const float* __restrict__ bias, float* __restrict__ out,
                              int B, int Cin, int Hin, int Win,
                              int Cout, int Hout, int Wout, int stride) {
    int total = B * Cout * Hout * Wout;
    int idx = blockIdx.x * blockDim.x + threadIdx.x;
    if (idx >= total) return;
    int wo = idx % Wout;
    int ho = (idx / Wout) % Hout;
    int co = (idx / (Wout * Hout)) % Cout;
    int b  = idx / (Wout * Hout * Cout);
    float acc = bias[co];
    int hb = ho * stride - 1, wb = wo * stride - 1;
    const float* wr = wgt + (size_t)co * Cin * 9;
    const float* ib = in + (size_t)b * Cin * Hin * Win;
    for (int ci = 0; ci < Cin; ++ci) {
        const float* ip = ib + (size_t)ci * Hin * Win;
        const float* wp = wr + ci * 9;
#pragma unroll
        for (int ky = 0; ky < 3; ++ky) {
            int hi = hb + ky;
            if (hi < 0 || hi >= Hin) continue;
#pragma unroll
            for (int kx = 0; kx < 3; ++kx) {
                int wi = wb + kx;
                if (wi < 0 || wi >= Win) continue;
                acc += ip[hi * Win + wi] * wp[ky * 3 + kx];
            }
        }
    }
    out[idx] = fmaxf(acc, 0.0f);
}

__global__ void conv3x3_hwc_k(const float* __restrict__ in, const float* __restrict__ wgt,
                              const float* __restrict__ bias, float* __restrict__ out,
                              int B, int Cin, int Hin, int Win,
                              int Cout, int Hout, int Wout, int stride) {
    int total = B * Cout * Hout * Wout;
    int idx = blockIdx.x * blockDim.x + threadIdx.x;
    if (idx >= total) return;
    int co = idx % Cout;
    int wo = (idx / Cout) % Wout;
    int ho = (idx / (Cout * Wout)) % Hout;
    int b  = idx / (Cout * Wout * Hout);
    float acc = bias[co];
    int hb = ho * stride - 1, wb = wo * stride - 1;
    const float* wr = wgt + (size_t)co * Cin * 9;
    const float* ib = in + (size_t)b * Cin * Hin * Win;
    for (int ci = 0; ci < Cin; ++ci) {
        const float* ip = ib + (size_t)ci * Hin * Win;
        const float* wp = wr + ci * 9;
#pragma unroll
        for (int ky = 0; ky < 3; ++ky) {
            int hi = hb + ky;
            if (hi < 0 || hi >= Hin) continue;
#pragma unroll
            for (int kx = 0; kx < 3; ++kx) {
                int wi = wb + kx;
                if (wi < 0 || wi >= Win) continue;
                acc += ip[hi * Win + wi] * wp[ky * 3 + kx];
            }
        }
    }
    out[idx] = fmaxf(acc, 0.0f);  // idx == HWC flat index
}

// ---- wave-per-output conv (HWC input, lane = ci) ---------------------------

__device__ __forceinline__ void wave_conv_one(
    const float* __restrict__ in, const float* __restrict__ wgt,
    const float* __restrict__ bias, float* __restrict__ out,
    int B, int Cin, int Hin, int Win, int Cout, int Hout, int Wout,
    int stride, int relu, int out_chw, int wid, int lane) {
    int copw = (Cin == 64) ? 1 : 2;
    int cow  = Cout / copw;
    int ci   = lane & (Cin - 1);
    int cw = wid % cow;
    int wo = (wid / cow) % Wout;
    int ho = (wid / (cow * Wout)) % Hout;
    int b  = wid / (cow * Wout * Hout);
    int co = cw * copw + ((copw == 2) ? (lane >> 5) : 0);
    int hb = ho * stride - 1, wb = wo * stride - 1;
    const float* wp = wgt + ((size_t)co * Cin + ci) * 9;
    float acc = 0.0f;
#pragma unroll
    for (int ky = 0; ky < 3; ++ky) {
        int hi = hb + ky;
        if (hi < 0 || hi >= Hin) continue;
#pragma unroll
        for (int kx = 0; kx < 3; ++kx) {
            int wi = wb + kx;
            if (wi < 0 || wi >= Win) continue;
            acc += in[((size_t)(b * Hin + hi) * Win + wi) * Cin + ci] * wp[ky * 3 + kx];
        }
    }
    for (int m = 1; m < Cin; m <<= 1) acc += __shfl_xor(acc, m);
    if (ci == 0) {
        if (bias) acc += bias[co];
        if (relu) acc = fmaxf(acc, 0.0f);
        if (out_chw) out[((size_t)(b * Cout + co) * Hout + ho) * Wout + wo] = acc;
        else         out[((size_t)(b * Hout + ho) * Wout + wo) * Cout + co] = acc;
    }
}

// conv3: 32->64, 32x32 -> 16x16, stride 2, HWC->HWC
__global__ void conv3_k(const float* __restrict__ x2, const float* __restrict__ w,
                        const float* __restrict__ bias, float* __restrict__ x3, int B) {
    int tid = blockIdx.x * blockDim.x + threadIdx.x;
    int wid = tid >> 6, lane = threadIdx.x & 63;
    int nw = B * 32 * 16 * 16;  // copw=2 -> 32 co-groups
    if (wid >= nw) return;
    wave_conv_one(x2, w, bias, x3, B, 32, 32, 32, 64, 16, 16, 2, 1, 0, wid, lane);
}

// gconv0 (64ch 16->8, s2) || lconv0 (64ch 16x16, s1, relu)
__global__ void gl0_k(const float* __restrict__ x3,
                      const float* __restrict__ gw, const float* __restrict__ gb, float* __restrict__ g0,
                      const float* __restrict__ lw, const float* __restrict__ lb, float* __restrict__ loc0,
                      int B) {
    int tid = blockIdx.x * blockDim.x + threadIdx.x;
    int wid = tid >> 6, lane = threadIdx.x & 63;
    int ng = B * 64 * 8 * 8;
    int nl = B * 64 * 16 * 16;
    if (wid < ng)            wave_conv_one(x3, gw, gb, g0,  B, 64, 16, 16, 64, 8, 8,  2, 1, 0, wid, lane);
    else if (wid < ng + nl)  wave_conv_one(x3, lw, lb, loc0, B, 64, 16, 16, 64, 16, 16, 1, 1, 0, wid - ng, lane);
}

// gconv1 (64ch 8->4, s2, CHW out for FC flatten) || lconv1 (no relu)
__global__ void gl1_k(const float* __restrict__ g0, const float* __restrict__ loc0,
                      const float* __restrict__ gw, const float* __restrict__ gb, float* __restrict__ g1,
                      const float* __restrict__ lw, float* __restrict__ loc1, int B) {
    int tid = blockIdx.x * blockDim.x + threadIdx.x;
    int wid = tid >> 6, lane = threadIdx.x & 63;
    int ng = B * 64 * 4 * 4;
    int nl = B * 64 * 16 * 16;
    if (wid < ng)            wave_conv_one(g0, gw, gb, g1,   B, 64, 8, 8,  64, 4, 4,  2, 1, 1, wid, lane);
    else if (wid < ng + nl)  wave_conv_one(loc0, lw, nullptr, loc1, B, 64, 16, 16, 64, 16, 16, 1, 0, 0, wid - ng, lane);
}

// fc0: wave per (b,o), 1024-dot, relu. out f0[b*256+o].
__global__ void fc0_k(const float* __restrict__ g1, const float* __restrict__ fw0,
                      const float* __restrict__ fb0, float* __restrict__ f0, int B) {
    int tid  = blockIdx.x * blockDim.x + threadIdx.x;
    int wid  = tid >> 6;
    int lane = threadIdx.x & 63;
    if (wid >= B * 256) return;
    int o = wid & 255, b = wid >> 8;
    const float* ip = g1 + (size_t)b * 1024;
    const float* wp = fw0 + (size_t)o * 1024;
    float acc = 0.0f;
    for (int j = lane; j < 1024; j += 64) acc += ip[j] * wp[j];
    for (int m = 1; m < 64; m <<= 1) acc += __shfl_xor(acc, m);
    if (lane == 0) f0[wid] = fmaxf(acc + fb0[o], 0.0f);
}

// ---- fused fc1 + fc2 + pred + guide + trilinear slice + affine apply -------
// One block per 64x64 pixel tile (grid = B*256). Preamble: fc1/fc2 computed
// per block from LDS-resident f0 (weights L2-hot), then pred over the tile's
// 3x3 grid-cell footprint into LDS, then per-pixel guide+slice+apply.

__global__ __launch_bounds__(256) void apply_k(
    const float* __restrict__ img, const float* __restrict__ loc1,
    const float* __restrict__ f0g,
    const float* __restrict__ fw1, const float* __restrict__ fb1,
    const float* __restrict__ fw2, const float* __restrict__ fb2,
    const float* __restrict__ pw, const float* __restrict__ pb,
    const float* __restrict__ ccm_w, const float* __restrict__ ccm_b,
    const float* __restrict__ shifts, const float* __restrict__ slopes,
    const float* __restrict__ proj_w, const float* __restrict__ proj_b,
    float* __restrict__ out) {
    __shared__ float s_pw[96 * 65];                 // padded
    __shared__ float s_pb[96];
    __shared__ __align__(16) float s_sco[9 * 96];   // 3x3 cells x (z*12+c)
    __shared__ __align__(16) float s_loc[9 * 64];
    __shared__ float s_f0[256];
    __shared__ float s_f1[128];
    __shared__ float s_f2[64];
    __shared__ float s_shift[48], s_slope[48], s_ccmw[9], s_ccmb[3], s_projw[3], s_projb[1];

    const int t   = threadIdx.x;
    const int b   = blockIdx.x >> 8;
    const int rem = blockIdx.x & 255;
    const int ty  = rem >> 4;
    const int tx  = rem & 15;
    const int wl   = t >> 6;      // wave 0..3
    const int lane = t & 63;

    // ---- stage params + f0 ----
    {
        const float4* pw4 = (const float4*)pw;      // [96][64] -> 1536 float4
        for (int j = t; j < 1536; j += 256) {
            float4 v = pw4[j];
            int base = j * 4;
            int c = base >> 6, i = base & 63;
            float* dst = &s_pw[c * 65 + i];
            dst[0] = v.x; dst[1] = v.y; dst[2] = v.z; dst[3] = v.w;
        }
        s_f0[t] = f0g[b * 256 + t];
        if (t < 96) s_pb[t] = pb[t];
        if (t < 48) { s_shift[t] = shifts[t]; s_slope[t] = slopes[t]; }
        if (t < 9)  s_ccmw[t] = ccm_w[t];
        if (t < 3)  { s_ccmb[t] = ccm_b[t]; s_projw[t] = proj_w[t]; }
        if (t == 0) s_projb[0] = proj_b[0];
        for (int j = t; j < 9 * 16; j += 256) {     // loc1: 9 cells x 64 ch as float4
            int cell = j >> 4, i4 = j & 15;
            int ly = cell / 3, lx = cell % 3;
            int gy = min(max(ty - 1 + ly, 0), 15);
            int gx = min(max(tx - 1 + lx, 0), 15);
            float4 v = ((const float4*)(loc1 + ((size_t)((b * 16 + gy) * 16 + gx)) * 64))[i4];
            ((float4*)(s_loc + cell * 64))[i4] = v;
        }
    }
    __syncthreads();

    // ---- fc1: 128 outputs, wave-dots of 256 (weights L2-hot) ----
    for (int o = wl; o < 128; o += 4) {
        const float* wp = fw1 + (size_t)o * 256;
        float acc = 0.0f;
#pragma unroll
        for (int j = lane; j < 256; j += 64) acc += s_f0[j] * wp[j];
        for (int m = 1; m < 64; m <<= 1) acc += __shfl_xor(acc, m);
        if (lane == 0) s_f1[o] = fmaxf(acc + fb1[o], 0.0f);
    }
    __syncthreads();
    // ---- fc2: 64 outputs, wave-dots of 128 (no relu) ----
    for (int o = wl; o < 64; o += 4) {
        const float* wp = fw2 + (size_t)o * 128;
        float acc = 0.0f;
#pragma unroll
        for (int j = lane; j < 128; j += 64) acc += s_f1[j] * wp[j];
        for (int m = 1; m < 64; m <<= 1) acc += __shfl_xor(acc, m);
        if (lane == 0) s_f2[o] = acc + fb2[o];
    }
    __syncthreads();

    // ---- pred: sco[cell][z*12+c] = pb + pw . relu(f2 + loc1[cell]) ----
    for (int o = t; o < 9 * 96; o += 256) {
        int cell = o / 96, c = o % 96;
        float acc = s_pb[c];
        const float* wp = &s_pw[c * 65];
        const float* lp = &s_loc[cell * 64];
        for (int i = 0; i < 64; ++i)
            acc += wp[i] * fmaxf(s_f2[i] + lp[i], 0.0f);
        s_sco[cell * 96 + c] = acc;
    }
    __syncthreads();

    // ---- per-pixel: guide -> slice (LDS) -> affine apply ----
    const size_t plane = 1024 * 1024;
    const float* ibase = img + (size_t)b * 3 * plane;
    float* obase = out + (size_t)b * 3 * plane;
    for (int it = 0; it < 16; ++it) {
        int pxi = it * 256 + t;
        int row = pxi >> 6, col = pxi & 63;
        int y = ty * 64 + row, x = tx * 64 + col;
        size_t off = (size_t)y * 1024 + x;
        float r  = ibase[off];
        float g  = ibase[plane + off];
        float bl = ibase[2 * plane + off];

        float gd = s_projb[0];
#pragma unroll
        for (int c = 0; c < 3; ++c) {
            float v = s_ccmb[c] + s_ccmw[c * 3 + 0] * r + s_ccmw[c * 3 + 1] * g + s_ccmw[c * 3 + 2] * bl;
            float acc = 0.0f;
#pragma unroll
            for (int p = 0; p < 16; ++p)
                acc += s_slope[c * 16 + p] * fmaxf(v - s_shift[c * 16 + p], 0.0f);
            gd += s_projw[c] * acc;
        }
        gd = fminf(fmaxf(gd, 0.0f), 1.0f);

        float xs = ((float)x + 0.5f) * 0.015625f - 0.5f;   // *16/1024
        float ys = ((float)y + 0.5f) * 0.015625f - 0.5f;
        float gz = gd * 8.0f - 0.5f;
        int fx = (int)floorf(xs);
        int fy = (int)floorf(ys);
        int fz = (int)floorf(gz);

        float coeff[12];
#pragma unroll
        for (int c = 0; c < 12; ++c) coeff[c] = 0.0f;

#pragma unroll
        for (int dz = 0; dz < 2; ++dz) {
            int zi = min(max(fz + dz, 0), 7);
            float wz = fmaxf(1.0f - fabsf(gz - (float)(fz + dz)), 0.0f);
#pragma unroll
            for (int dy = 0; dy < 2; ++dy) {
                int ly = (fy + dy) - (ty - 1);             // in {0,1,2}; staging clamped
                float wy = fmaxf(1.0f - fabsf(ys - (float)(fy + dy)), 0.0f);
#pragma unroll
                for (int dx = 0; dx < 2; ++dx) {
                    int lx = (fx + dx) - (tx - 1);         // in {0,1,2}
                    float wx = fmaxf(1.0f - fabsf(xs - (float)(fx + dx)), 0.0f);
                    float wt = wz * wy * wx;
                    const float4* gp = (const float4*)(s_sco + ((ly * 3 + lx) * 96 + zi * 12));
                    float4 a0 = gp[0], a1 = gp[1], a2 = gp[2];
                    coeff[0]  += wt * a0.x; coeff[1]  += wt * a0.y; coeff[2]  += wt * a0.z; coeff[3]  += wt * a0.w;
                    coeff[4]  += wt * a1.x; coeff[5]  += wt * a1.y; coeff[6]  += wt * a1.z; coeff[7]  += wt * a1.w;
                    coeff[8]  += wt * a2.x; coeff[9]  += wt * a2.y; coeff[10] += wt * a2.z; coeff[11] += wt * a2.w;
                }
            }
        }

#pragma unroll
        for (int o = 0; o < 3; ++o) {
            float v = coeff[o * 4 + 3] + coeff[o * 4 + 0] * r + coeff[o * 4 + 1] * g + coeff[o * 4 + 2] * bl;
            obase[o * plane + off] = fminf(fmaxf(v, 0.0f), 1.0f);
        }
    }
}

// ---------------------------------------------------------------------------

extern "C" void kernel_launch(void* const* d_in, const int* in_sizes, int n_in,
                              void* d_out, int out_size, void* d_ws, size_t ws_size,
                              hipStream_t stream) {
    const float* img_lo = (const float*)d_in[0];
    const float* img_fr = (const float*)d_in[1];
    const float* sw0 = (const float*)d_in[2];  const float* sb0 = (const float*)d_in[3];
    const float* sw1 = (const float*)d_in[4];  const float* sb1 = (const float*)d_in[5];
    const float* sw2 = (const float*)d_in[6];  const float* sb2 = (const float*)d_in[7];
    const float* sw3 = (const float*)d_in[8];  const float* sb3 = (const float*)d_in[9];
    const float* gw0 = (const float*)d_in[10]; const float* gb0 = (const float*)d_in[11];
    const float* gw1 = (const float*)d_in[12]; const float* gb1 = (const float*)d_in[13];
    const float* fw0 = (const float*)d_in[14]; const float* fb0 = (const float*)d_in[15];
    const float* fw1 = (const float*)d_in[16]; const float* fb1 = (const float*)d_in[17];
    const float* fw2 = (const float*)d_in[18]; const float* fb2 = (const float*)d_in[19];
    const float* lw0 = (const float*)d_in[20]; const float* lb0 = (const float*)d_in[21];
    const float* lw1 = (const float*)d_in[22];
    const float* pw  = (const float*)d_in[23]; const float* pb  = (const float*)d_in[24];
    const float* ccm_w  = (const float*)d_in[25]; const float* ccm_b = (const float*)d_in[26];
    const float* shifts = (const float*)d_in[27];
    const float* slopes = (const float*)d_in[28];
    const float* proj_w = (const float*)d_in[29];
    const float* proj_b = (const float*)d_in[30];
    float* out = (float*)d_out;

    const int B = in_sizes[0] / (3 * 256 * 256);   // = 2

    // workspace carve (floats)
    float* ws = (float*)d_ws;
    float* x0   = ws;                                // B*8*128*128   CHW
    float* x1   = x0 + (size_t)B * 8  * 128 * 128;   // B*16*64*64    CHW
    float* x2   = x1 + (size_t)B * 16 * 64 * 64;     // B*32*32*32    HWC
    float* x3   = x2 + (size_t)B * 32 * 32 * 32;     // B*16*16*64    HWC
    float* g0   = x3 + (size_t)B * 64 * 16 * 16;     // B*8*8*64      HWC
    float* g1   = g0 + (size_t)B * 64 * 8 * 8;       // B*64*4*4      CHW
    float* f0   = g1 + (size_t)B * 64 * 4 * 4;       // B*256
    float* loc0 = f0 + (size_t)B * 256;              // B*16*16*64    HWC
    float* loc1 = loc0 + (size_t)B * 64 * 16 * 16;   // B*16*16*64    HWC

    const int T = 256;

    // 1-3: splat chain (wide)
    conv3x3_chw_k<<<cdiv(B * 8 * 128 * 128, T), T, 0, stream>>>(img_lo, sw0, sb0, x0, B, 3, 256, 256, 8, 128, 128, 2);
    conv3x3_chw_k<<<cdiv(B * 16 * 64 * 64, T), T, 0, stream>>>(x0, sw1, sb1, x1, B, 8, 128, 128, 16, 64, 64, 2);
    conv3x3_hwc_k<<<cdiv(B * 32 * 32 * 32, T), T, 0, stream>>>(x1, sw2, sb2, x2, B, 16, 64, 64, 32, 32, 32, 2);
    // 4: conv3 (wave)
    conv3_k<<<cdiv(B * 32 * 16 * 16 * 64, T), T, 0, stream>>>(x2, sw3, sb3, x3, B);
    // 5: gconv0 || lconv0
    {
        int nwaves = B * 64 * 8 * 8 + B * 64 * 16 * 16;
        gl0_k<<<cdiv(nwaves * 64, T), T, 0, stream>>>(x3, gw0, gb0, g0, lw0, lb0, loc0, B);
    }
    // 6: gconv1 || lconv1
    {
        int nwaves = B * 64 * 4 * 4 + B * 64 * 16 * 16;
        gl1_k<<<cdiv(nwaves * 64, T), T, 0, stream>>>(g0, loc0, gw1, gb1, g1, lw1, loc1, B);
    }
    // 7: fc0 (wide, wave per output)
    fc0_k<<<cdiv(B * 256 * 64, T), T, 0, stream>>>(g1, fw0, fb0, f0, B);
    // 8: fused fc1+fc2+pred+guide+slice+apply (64x64-px tiles)
    apply_k<<<B * 256, 256, 0, stream>>>(img_fr, loc1, f0, fw1, fb1, fw2, fb2,
                                         pw, pb, ccm_w, ccm_b, shifts, slopes,
                                         proj_w, proj_b, out);
}